// Round 11
// baseline (25262.573 us; speedup 1.0000x reference)
//
#include <hip/hip_runtime.h>
#include <hip/hip_bf16.h>

// Problem constants (match the reference)
constexpr int B = 4;
constexpr int N = 16384;
constexpr int S = 4096;       // N * 0.25
constexpr int K = 32;
constexpr float BIG = 1e30f;

// Output layout (flat f32, concatenated in reference return order)
constexpr size_t OFF_COORD = 0;                       // node_coord_dst [B*S*3]
constexpr size_t OFF_ESRC  = (size_t)B * S * 3;       // edge_src [B*S*K]
constexpr size_t OFF_EDST  = OFF_ESRC + (size_t)B * S * K;
constexpr size_t OFF_MASK  = OFF_EDST + (size_t)B * S * K;
constexpr size_t OFF_DEG   = OFF_MASK + (size_t)B * S * K;
constexpr size_t OFF_BATCH = OFF_DEG + (size_t)B * S;
constexpr size_t OFF_NIDX  = OFF_BATCH + (size_t)B * S;

// ============ Kernel 0: Morton counting-sort (one block per cloud) =========
#define NT_MS 1024
__global__ __launch_bounds__(NT_MS)
void morton_sort_kernel(const float* __restrict__ pts, float4* __restrict__ sbuf) {
    const int b = blockIdx.x, t = threadIdx.x;
    const int lane = t & 63, wave = t >> 6;
    const float* p = pts + (size_t)b * N * 3;
    float4* sb = sbuf + (size_t)b * N;

    __shared__ unsigned int cnt[8192];   // 16384 u16 counters packed
    __shared__ int s_wsum[16];

    for (int i = t; i < 8192; i += NT_MS) cnt[i] = 0u;
    __syncthreads();

    float xx[16], yy[16], zz[16];
    int code[16];
#pragma unroll
    for (int j = 0; j < 16; ++j) {
        int i = t + j * NT_MS;
        float x = p[i * 3 + 0], y = p[i * 3 + 1], z = p[i * 3 + 2];
        xx[j] = x; yy[j] = y; zz[j] = z;
        int xi = min(31, (int)(x * 32.0f));
        int yi = min(31, (int)(y * 32.0f));
        int zi = min(15, (int)(z * 16.0f));
        int c = 0;
#pragma unroll
        for (int k = 0; k < 4; ++k) {
            c |= ((zi >> k) & 1) << (3 * k);
            c |= ((yi >> k) & 1) << (3 * k + 1);
            c |= ((xi >> k) & 1) << (3 * k + 2);
        }
        c |= ((xi >> 4) & 1) << 12;
        c |= ((yi >> 4) & 1) << 13;
        code[j] = c;
        atomicAdd(&cnt[c >> 1], (c & 1) ? 0x10000u : 1u);
    }
    __syncthreads();

    unsigned int w[8];
    int tot = 0;
#pragma unroll
    for (int k = 0; k < 8; ++k) {
        w[k] = cnt[t * 8 + k];
        tot += (int)(w[k] & 0xffffu) + (int)(w[k] >> 16);
    }
    int inc = tot;
#pragma unroll
    for (int off = 1; off < 64; off <<= 1) {
        int v = __shfl_up(inc, off);
        if (lane >= off) inc += v;
    }
    if (lane == 63) s_wsum[wave] = inc;
    __syncthreads();
    int wbase = 0;
#pragma unroll
    for (int q = 0; q < 16; ++q) {
        int v = s_wsum[q];
        if (q < wave) wbase += v;
    }
    int excl = wbase + inc - tot;
#pragma unroll
    for (int k = 0; k < 8; ++k) {
        unsigned int c0 = (unsigned int)excl;
        unsigned int c1 = c0 + (w[k] & 0xffffu);
        cnt[t * 8 + k] = c0 | (c1 << 16);
        excl = (int)(c1 + (w[k] >> 16));
    }
    __syncthreads();

#pragma unroll
    for (int j = 0; j < 16; ++j) {
        int i = t + j * NT_MS;
        int c = code[j];
        unsigned int old = atomicAdd(&cnt[c >> 1], (c & 1) ? 0x10000u : 1u);
        int pos = (c & 1) ? (int)(old >> 16) : (int)(old & 0xffffu);
        sb[pos] = make_float4(xx[j], yy[j], zz[j], __int_as_float(i));
    }
}

// ============ Kernel 1: candidate-list FPS (one block per cloud) ============
// Exact FPS (validated absmax=0 in round 10). Round-11 changes ONLY:
//  (1) conflict-free key layout addr(j,t)=j*NT_FP+t (was t*CPT+j: 128B lane
//      stride -> 32-way bank conflict -> 4.9e7 conflict-cycles = ~20 ms).
//      Chunk = contiguous Morton range [t*16,t*16+16) in sbuf, unchanged;
//      only the LDS address permutes. addr -> (t = addr&1023, j = addr>>10,
//      sbuf idx = t*16+j).
//  (2) finer theta ladder {0.30,...,0.93}, pick SMALLEST f with 0<n<=128
//      (bigger list -> longer cheap runs -> fewer rebuilds).
#define NT_FP 1024
#define CPT 16
#define LISTCAP 128
#define PENDCAP 64          // pending-center hotmask fits one u64
#define BOOT 64             // steps before first list build
#define NLAD 6

__global__ __launch_bounds__(NT_FP, 1)
void fps_pruned_kernel(const float* __restrict__ pts, const float4* __restrict__ sbuf,
                       int* __restrict__ seq) {
    const int b = blockIdx.x, t = threadIdx.x;
    const int lane = t & 63, wave = t >> 6;
    const float4* sb = sbuf + (size_t)b * N;

    __shared__ unsigned long long s_key[N];          // 128 KB, addr j*NT_FP+t
    __shared__ unsigned long long s_lkey[LISTCAP];
    __shared__ float s_lx[LISTCAP], s_ly[LISTCAP], s_lz[LISTCAP];
    __shared__ int   s_lslot[LISTCAP];               // stores ADDR
    __shared__ float s_px[PENDCAP], s_py[PENDCAP], s_pz[PENDCAP];
    __shared__ unsigned int s_dirty[NT_FP / 32];
    __shared__ unsigned long long s_red;
    __shared__ int s_cnt[NLAD];
    __shared__ int s_listcnt;
    __shared__ int s_npend;
    __shared__ int s_step;
    __shared__ float s_wx, s_wy, s_wz;
    __shared__ unsigned long long s_theta;

    float bx0 = BIG, by0 = BIG, bz0 = BIG, bx1 = -BIG, by1 = -BIG, bz1 = -BIG;
#pragma unroll
    for (int j = 0; j < CPT; ++j) {
        float4 v = sb[t * CPT + j];
        s_key[j * NT_FP + t] =
            ((unsigned long long)__float_as_uint(BIG) << 32) |
            (~(unsigned int)__float_as_int(v.w));
        bx0 = fminf(bx0, v.x); bx1 = fmaxf(bx1, v.x);
        by0 = fminf(by0, v.y); by1 = fmaxf(by1, v.y);
        bz0 = fminf(bz0, v.z); bz1 = fmaxf(bz1, v.z);
    }
    unsigned long long bkey =
        ((unsigned long long)__float_as_uint(BIG) << 32) | 0xFFFFFFFFull;
    int bj = 0;     // valid whenever bkey recomputed (first rebuild: all hot)

    if (t == 0) {
        const float* p = pts + (size_t)b * N * 3;
        seq[b * S + 0] = 0;                  // random_start=False
        s_px[0] = p[0]; s_py[0] = p[1]; s_pz[0] = p[2];
        s_npend = 1; s_step = 1;
        s_theta = ~0ull;                     // guard always fails -> rebuild
        s_listcnt = 0; s_red = 0ull;
    }
    if (t < NT_FP / 32) s_dirty[t] = 0u;
    if (t < NLAD) s_cnt[t] = 0;
    __syncthreads();

    for (;;) {
        // -------- cheap phase: wave 0 only (others wait at the barrier) -----
        if (wave == 0) {
            const int lc = s_listcnt;
            const unsigned long long th = s_theta;
            unsigned long long k0 = 0ull, k1 = 0ull;
            float ex0 = 0.f, ey0 = 0.f, ez0 = 0.f;
            float ex1 = 0.f, ey1 = 0.f, ez1 = 0.f;
            int sl0 = 0, sl1 = 0;
            if (lane < lc) {
                k0 = s_lkey[lane]; ex0 = s_lx[lane];
                ey0 = s_ly[lane];  ez0 = s_lz[lane]; sl0 = s_lslot[lane];
            }
            if (lane + 64 < lc) {
                k1 = s_lkey[lane + 64]; ex1 = s_lx[lane + 64];
                ey1 = s_ly[lane + 64];  ez1 = s_lz[lane + 64];
                sl1 = s_lslot[lane + 64];
            }
            int np = s_npend;
            int st = s_step;
            float cx = s_px[np - 1], cy = s_py[np - 1], cz = s_pz[np - 1];
            while (st < S && np < PENDCAP) {
                {   // exact update of entry 0 vs newest center
                    float dx = __fsub_rn(ex0, cx), dy = __fsub_rn(ey0, cy),
                          dz = __fsub_rn(ez0, cz);
                    float d = __fadd_rn(__fadd_rn(__fmul_rn(dx, dx),
                              __fmul_rn(dy, dy)), __fmul_rn(dz, dz));
                    float v = __uint_as_float((unsigned int)(k0 >> 32));
                    float nv = fminf(v, d);
                    k0 = ((unsigned long long)__float_as_uint(nv) << 32) |
                         (unsigned int)k0;
                }
                {   // entry 1
                    float dx = __fsub_rn(ex1, cx), dy = __fsub_rn(ey1, cy),
                          dz = __fsub_rn(ez1, cz);
                    float d = __fadd_rn(__fadd_rn(__fmul_rn(dx, dx),
                              __fmul_rn(dy, dy)), __fmul_rn(dz, dz));
                    float v = __uint_as_float((unsigned int)(k1 >> 32));
                    float nv = fminf(v, d);
                    k1 = ((unsigned long long)__float_as_uint(nv) << 32) |
                         (unsigned int)k1;
                }
                unsigned long long mk = (k0 > k1) ? k0 : k1;
                unsigned long long r = mk;
#pragma unroll
                for (int off = 32; off >= 1; off >>= 1) {
                    unsigned long long o = __shfl_xor(r, off);
                    r = (o > r) ? o : r;
                }
                if (r <= th) break;            // winner might be off-list
                unsigned long long mask = __ballot(mk == r);   // keys unique
                int wl = (int)__builtin_ctzll(mask);
                int sel = (k1 == r) ? 1 : 0;                   // on lane wl
                float wx = __shfl(sel ? ex1 : ex0, wl);
                float wy = __shfl(sel ? ey1 : ey0, wl);
                float wz = __shfl(sel ? ez1 : ez0, wl);
                int   ws = __shfl(sel ? sl1 : sl0, wl);
                if (lane == wl) { if (sel) k1 = 0ull; else k0 = 0ull; }
                if (lane == 0) {
                    seq[b * S + st] = (int)(~(unsigned int)r);
                    s_key[ws] = 0ull;          // consumed: dd -> 0 (exact)
                    int owner = ws & (NT_FP - 1);
                    atomicOr(&s_dirty[owner >> 5], 1u << (owner & 31));
                    s_px[np] = wx; s_py[np] = wy; s_pz[np] = wz;
                }
                cx = wx; cy = wy; cz = wz;
                ++np; ++st;
            }
            if (lane == 0) { s_step = st; s_npend = np; }
        }
        __syncthreads();                                       // B0
        const int step = s_step;
        if (step >= S) break;
        const int np = s_npend;

        // -------- rebuild: batch-apply pending centers (bbox-pruned) -------
        if (t == 0) s_listcnt = 0;
        if (t < NLAD) s_cnt[t] = 0;
        {
            unsigned long long hot = 0ull;
            const float bmax0 = __uint_as_float((unsigned int)(bkey >> 32));
            for (int c = 0; c < np; ++c) {
                float cx = s_px[c], cy = s_py[c], cz = s_pz[c];
                float tx = fmaxf(fmaxf(bx0 - cx, cx - bx1), 0.0f);
                float ty = fmaxf(fmaxf(by0 - cy, cy - by1), 0.0f);
                float tz = fmaxf(fmaxf(bz0 - cz, cz - bz1), 0.0f);
                float lb = tx * tx + ty * ty + tz * tz;
                if (lb * 0.999998f < bmax0) hot |= (1ull << c);
            }
            bool dirty = (s_dirty[t >> 5] >> (t & 31)) & 1u;
            if (hot) {
                unsigned long long m = 0ull; int mj = 0;
#pragma unroll
                for (int j = 0; j < CPT; ++j) {
                    float4 v = sb[t * CPT + j];             // L2-resident
                    int addr = j * NT_FP + t;
                    unsigned long long k = s_key[addr];
                    float val = __uint_as_float((unsigned int)(k >> 32));
                    unsigned long long hh = hot;
                    while (hh) {
                        int c = (int)__builtin_ctzll(hh); hh &= hh - 1;
                        float dx = __fsub_rn(v.x, s_px[c]);
                        float dy = __fsub_rn(v.y, s_py[c]);
                        float dz = __fsub_rn(v.z, s_pz[c]);
                        float d = __fadd_rn(__fadd_rn(__fmul_rn(dx, dx),
                                  __fmul_rn(dy, dy)), __fmul_rn(dz, dz));
                        val = fminf(val, d);            // exact running min
                    }
                    k = ((unsigned long long)__float_as_uint(val) << 32) |
                        (unsigned int)k;
                    s_key[addr] = k;
                    if (k > m) { m = k; mj = j; }
                }
                bkey = m; bj = mj;
            } else if (dirty) {                         // consumed point here
                unsigned long long m = 0ull; int mj = 0;
#pragma unroll
                for (int j = 0; j < CPT; ++j) {
                    unsigned long long k = s_key[j * NT_FP + t];
                    if (k > m) { m = k; mj = j; }
                }
                bkey = m; bj = mj;
            }
            // block argmax of exact per-chunk maxima
            unsigned long long r = bkey;
#pragma unroll
            for (int off = 32; off >= 1; off >>= 1) {
                unsigned long long o = __shfl_xor(r, off);
                r = (o > r) ? o : r;
            }
            if (lane == 0) atomicMax((unsigned long long*)&s_red, r);
        }
        __syncthreads();                                       // B1
        const unsigned long long g = s_red;
        if (bkey == g) {                    // unique owner (keys unique)
            float4 v = sb[t * CPT + bj];
            seq[b * S + step] = (int)(~(unsigned int)g);
            s_wx = v.x; s_wy = v.y; s_wz = v.z;
            s_key[bj * NT_FP + t] = 0ull;   // consumed
            unsigned long long m = 0ull; int mj = 0;
#pragma unroll
            for (int j = 0; j < CPT; ++j) {
                unsigned long long k = s_key[j * NT_FP + t];
                if (k > m) { m = k; mj = j; }
            }
            bkey = m; bj = mj;
        }
        if (t < NT_FP / 32) s_dirty[t] = 0u;
        {
            // counts vs NLAD theta candidates (own chunk only -> no races)
            float vmax = __uint_as_float((unsigned int)(g >> 32));
            const float lf[NLAD] = {0.30f, 0.45f, 0.60f, 0.72f, 0.84f, 0.93f};
            int cc[NLAD];
#pragma unroll
            for (int q = 0; q < NLAD; ++q) cc[q] = 0;
#pragma unroll
            for (int j = 0; j < CPT; ++j) {
                unsigned long long k = s_key[j * NT_FP + t];
                float kv = __uint_as_float((unsigned int)(k >> 32));
#pragma unroll
                for (int q = 0; q < NLAD; ++q)
                    cc[q] += (kv > vmax * lf[q]);
            }
#pragma unroll
            for (int off = 32; off >= 1; off >>= 1) {
#pragma unroll
                for (int q = 0; q < NLAD; ++q)
                    cc[q] += __shfl_xor(cc[q], off);
            }
            if (lane == 0) {
#pragma unroll
                for (int q = 0; q < NLAD; ++q)
                    if (cc[q]) atomicAdd(&s_cnt[q], cc[q]);
            }
        }
        __syncthreads();                                       // B2
        {
            float vmax = __uint_as_float((unsigned int)(g >> 32));
            const float lf[NLAD] = {0.30f, 0.45f, 0.60f, 0.72f, 0.84f, 0.93f};
            float f = -1.0f;
#pragma unroll
            for (int q = 0; q < NLAD; ++q) {
                int n = s_cnt[q];
                if (f < 0.0f && n > 0 && n <= LISTCAP) f = lf[q];
            }
            bool dolist = (f > 0.0f) && (step >= BOOT);
            unsigned long long thk = dolist
                ? (((unsigned long long)__float_as_uint(vmax * f) << 32) |
                   0xFFFFFFFFull)
                : ~0ull;
            if (t == 0) {
                s_theta = thk; s_red = 0ull; s_step = step + 1;
                s_npend = 1; s_px[0] = s_wx; s_py[0] = s_wy; s_pz[0] = s_wz;
            }
            if (dolist) {
#pragma unroll
                for (int j = 0; j < CPT; ++j) {
                    int addr = j * NT_FP + t;
                    unsigned long long k = s_key[addr];
                    // match the count predicate exactly (value comparison)
                    if (k > thk) {
                        int pos = atomicAdd(&s_listcnt, 1);
                        if (pos < LISTCAP) {
                            float4 v = sb[t * CPT + j];
                            s_lkey[pos] = k; s_lx[pos] = v.x;
                            s_ly[pos] = v.y; s_lz[pos] = v.z;
                            s_lslot[pos] = addr;
                        }
                    }
                }
            }
        }
        __syncthreads();                                       // B3
    }
}

// ============ Fallback FPS (used only if ws too small) ======================
#define NT_FPS 512
#define PPT (N / NT_FPS)
#define NWAVE (NT_FPS / 64)
__global__ __launch_bounds__(NT_FPS)
void fps_kernel(const float* __restrict__ pts, int* __restrict__ seq) {
    const int b = blockIdx.x;
    const float* p = pts + (size_t)b * N * 3;
    const int t = threadIdx.x;
    const int lane = t & 63;
    const int wave = t >> 6;
    float px[PPT], py[PPT], pz[PPT], dd[PPT];
    const int base = t * PPT;
#pragma unroll
    for (int j = 0; j < PPT; ++j) {
        px[j] = p[(base + j) * 3 + 0];
        py[j] = p[(base + j) * 3 + 1];
        pz[j] = p[(base + j) * 3 + 2];
        dd[j] = BIG;
    }
#pragma unroll
    for (int j = 0; j < PPT; ++j)
        asm volatile("" : "+v"(px[j]), "+v"(py[j]), "+v"(pz[j]));
    __shared__ unsigned long long s_part[2][NWAVE];
    if (t == 0) seq[b * S + 0] = 0;
    float lx = p[0], ly = p[1], lz = p[2];
    for (int step = 1; step < S; ++step) {
        float bv = -1.0f;
        int bi = 0;
#pragma unroll
        for (int j = 0; j < PPT; ++j) {
            float dx = __fsub_rn(px[j], lx);
            float dy = __fsub_rn(py[j], ly);
            float dz = __fsub_rn(pz[j], lz);
            float d  = __fadd_rn(__fadd_rn(__fmul_rn(dx, dx), __fmul_rn(dy, dy)),
                                 __fmul_rn(dz, dz));
            float nd = fminf(dd[j], d);
            dd[j] = nd;
            if (nd > bv) { bv = nd; bi = base + j; }
        }
        unsigned long long key =
            ((unsigned long long)__float_as_uint(bv) << 32) | (unsigned int)(~bi);
#pragma unroll
        for (int off = 32; off >= 1; off >>= 1) {
            unsigned long long o = __shfl_down(key, off);
            if (o > key) key = o;
        }
        if (lane == 0) s_part[step & 1][wave] = key;
        __syncthreads();
        unsigned long long bk = s_part[step & 1][0];
#pragma unroll
        for (int q = 1; q < NWAVE; ++q) {
            unsigned long long o = s_part[step & 1][q];
            if (o > bk) bk = o;
        }
        int wi = (int)(~(unsigned int)bk);
        if (t == 0) seq[b * S + step] = wi;
        int wis = __builtin_amdgcn_readfirstlane(wi);
        lx = p[wis * 3 + 0];
        ly = p[wis * 3 + 1];
        lz = p[wis * 3 + 2];
    }
}

// ============ Kernel 2: sort FPS indices (bitmap rank), gather dst ==========
#define NT_SORT 512
__global__ __launch_bounds__(NT_SORT)
void sort_gather_kernel(const float* __restrict__ pts, const int* __restrict__ seq,
                        int* __restrict__ sorted, float* __restrict__ out) {
    const int b = blockIdx.x;
    const int t = threadIdx.x;
    __shared__ unsigned int bm[N / 32];
    __shared__ int pfx[N / 32];
    __shared__ int s_sorted[S];

    for (int i = t; i < N / 32; i += NT_SORT) bm[i] = 0u;
    __syncthreads();
    for (int i = t; i < S; i += NT_SORT) {
        int v = seq[b * S + i];
        atomicOr(&bm[v >> 5], 1u << (v & 31));
    }
    __syncthreads();

    int myc = __popc(bm[t]);
    pfx[t] = myc;
    __syncthreads();
    for (int off = 1; off < N / 32; off <<= 1) {
        int v = (t >= off) ? pfx[t - off] : 0;
        __syncthreads();
        pfx[t] += v;
        __syncthreads();
    }

    for (int i = t; i < S; i += NT_SORT) {
        int v = seq[b * S + i];
        int w = v >> 5;
        int rank = pfx[w] - __popc(bm[w]) + __popc(bm[w] & ((1u << (v & 31)) - 1u));
        s_sorted[rank] = v;
    }
    __syncthreads();

    for (int r = t; r < S; r += NT_SORT) {
        int v = s_sorted[r];
        int g = b * S + r;
        sorted[g] = v;
        out[OFF_COORD + 3 * (size_t)g + 0] = pts[((size_t)b * N + v) * 3 + 0];
        out[OFF_COORD + 3 * (size_t)g + 1] = pts[((size_t)b * N + v) * 3 + 1];
        out[OFF_COORD + 3 * (size_t)g + 2] = pts[((size_t)b * N + v) * 3 + 2];
        out[OFF_BATCH + g] = (float)b;
        out[OFF_NIDX + g]  = (float)(v + b * N);
    }
}

// ============ Kernel 3: radius ball query, one wave per dst point ===========
#define CAP 512
__global__ __launch_bounds__(256)
void ballq_kernel(const float* __restrict__ pts, const int* __restrict__ sorted,
                  float* __restrict__ out) {
    const int w    = threadIdx.x >> 6;
    const int lane = threadIdx.x & 63;
    const int g    = blockIdx.x * 4 + w;
    const int b    = g >> 12;
    const float R2 = (float)(0.08 * 0.08);

    __shared__ float cd2[4][CAP];
    __shared__ int   cidx[4][CAP];
    __shared__ int   coor[4][K];

    const float Dx = out[OFF_COORD + 3 * (size_t)g + 0];
    const float Dy = out[OFF_COORD + 3 * (size_t)g + 1];
    const float Dz = out[OFF_COORD + 3 * (size_t)g + 2];
    const int self = sorted[g];

    const float* p = pts + (size_t)b * N * 3;
    const unsigned long long ltmask = (lane == 63) ? 0x7fffffffffffffffull
                                                   : ((1ull << lane) - 1ull);
    int cnt = 0, oor = 0;
    for (int i0 = 0; i0 < N; i0 += 64) {
        int i = i0 + lane;
        float dx = __fsub_rn(Dx, p[i * 3 + 0]);
        float dy = __fsub_rn(Dy, p[i * 3 + 1]);
        float dz = __fsub_rn(Dz, p[i * 3 + 2]);
        float d2 = __fadd_rn(__fadd_rn(__fmul_rn(dx, dx), __fmul_rn(dy, dy)),
                             __fmul_rn(dz, dz));
        bool in = (d2 <= R2);
        unsigned long long m = __ballot(in);
        if (in) {
            int pos = cnt + __popcll(m & ltmask);
            if (pos < CAP) { cd2[w][pos] = d2; cidx[w][pos] = i; }
        }
        if (oor < K) {
            unsigned long long m2 = ~m;
            if (!in) {
                int p2 = oor + __popcll(m2 & ltmask);
                if (p2 < K) coor[w][p2] = i;
            }
            oor += __popcll(m2);
            if (oor > K) oor = K;
        }
        cnt += __popcll(m);
    }

    const int M  = cnt < CAP ? cnt : CAP;
    const int Mk = M < K ? M : K;
    const size_t eb = (size_t)g * K;
    int deg = 0;
    for (int c = lane; c < M; c += 64) {
        float myd = cd2[w][c];
        int   myi = cidx[w][c];
        int rank = 0;
        for (int j = 0; j < M; ++j) {
            float dj = cd2[w][j];
            int   ij = cidx[w][j];
            rank += (dj < myd || (dj == myd && ij < myi)) ? 1 : 0;
        }
        if (rank < K) {
            bool valid = (myi != self);
            out[OFF_ESRC + eb + rank] = (float)(myi + b * N);
            out[OFF_MASK + eb + rank] = valid ? 1.0f : 0.0f;
            deg += valid ? 1 : 0;
        }
    }
    for (int r = lane; r < K; r += 64) {
        out[OFF_EDST + eb + r] = (float)g;
        if (r >= Mk) {
            out[OFF_ESRC + eb + r] = (float)(coor[w][r - Mk] + b * N);
            out[OFF_MASK + eb + r] = 0.0f;
        }
    }
#pragma unroll
    for (int off = 32; off >= 1; off >>= 1) deg += __shfl_down(deg, off);
    if (lane == 0) out[OFF_DEG + g] = (float)deg;
}

extern "C" void kernel_launch(void* const* d_in, const int* in_sizes, int n_in,
                              void* d_out, int out_size, void* d_ws, size_t ws_size,
                              hipStream_t stream) {
    const float* pts = (const float*)d_in[0];
    float* out = (float*)d_out;

    const size_t sbuf_bytes = (size_t)B * N * sizeof(float4);   // 1 MB
    const size_t need = sbuf_bytes + 2 * (size_t)B * S * sizeof(int);

    if (ws_size >= need) {
        float4* sbuf = (float4*)d_ws;
        int* seq    = (int*)((char*)d_ws + sbuf_bytes);
        int* sorted = seq + (size_t)B * S;
        morton_sort_kernel<<<B, NT_MS, 0, stream>>>(pts, sbuf);
        fps_pruned_kernel<<<B, NT_FP, 0, stream>>>(pts, sbuf, seq);
        sort_gather_kernel<<<B, NT_SORT, 0, stream>>>(pts, seq, sorted, out);
        ballq_kernel<<<(B * S) / 4, 256, 0, stream>>>(pts, sorted, out);
    } else {
        int* seq    = (int*)d_ws;
        int* sorted = seq + (size_t)B * S;
        fps_kernel<<<B, NT_FPS, 0, stream>>>(pts, seq);
        sort_gather_kernel<<<B, NT_SORT, 0, stream>>>(pts, seq, sorted, out);
        ballq_kernel<<<(B * S) / 4, 256, 0, stream>>>(pts, sorted, out);
    }
}

// Round 12
// 8169.369 us; speedup vs baseline: 3.0924x; 3.0924x over previous
//
#include <hip/hip_runtime.h>
#include <hip/hip_bf16.h>

// Problem constants (match the reference)
constexpr int B = 4;
constexpr int N = 16384;
constexpr int S = 4096;       // N * 0.25
constexpr int K = 32;
constexpr float BIG = 1e30f;

// Output layout (flat f32, concatenated in reference return order)
constexpr size_t OFF_COORD = 0;                       // node_coord_dst [B*S*3]
constexpr size_t OFF_ESRC  = (size_t)B * S * 3;       // edge_src [B*S*K]
constexpr size_t OFF_EDST  = OFF_ESRC + (size_t)B * S * K;
constexpr size_t OFF_MASK  = OFF_EDST + (size_t)B * S * K;
constexpr size_t OFF_DEG   = OFF_MASK + (size_t)B * S * K;
constexpr size_t OFF_BATCH = OFF_DEG + (size_t)B * S;
constexpr size_t OFF_NIDX  = OFF_BATCH + (size_t)B * S;

// ============ Kernel 0: Morton counting-sort (one block per cloud) =========
#define NT_MS 1024
__global__ __launch_bounds__(NT_MS)
void morton_sort_kernel(const float* __restrict__ pts, float4* __restrict__ sbuf) {
    const int b = blockIdx.x, t = threadIdx.x;
    const int lane = t & 63, wave = t >> 6;
    const float* p = pts + (size_t)b * N * 3;
    float4* sb = sbuf + (size_t)b * N;

    __shared__ unsigned int cnt[8192];   // 16384 u16 counters packed
    __shared__ int s_wsum[16];

    for (int i = t; i < 8192; i += NT_MS) cnt[i] = 0u;
    __syncthreads();

    float xx[16], yy[16], zz[16];
    int code[16];
#pragma unroll
    for (int j = 0; j < 16; ++j) {
        int i = t + j * NT_MS;
        float x = p[i * 3 + 0], y = p[i * 3 + 1], z = p[i * 3 + 2];
        xx[j] = x; yy[j] = y; zz[j] = z;
        int xi = min(31, (int)(x * 32.0f));
        int yi = min(31, (int)(y * 32.0f));
        int zi = min(15, (int)(z * 16.0f));
        int c = 0;
#pragma unroll
        for (int k = 0; k < 4; ++k) {
            c |= ((zi >> k) & 1) << (3 * k);
            c |= ((yi >> k) & 1) << (3 * k + 1);
            c |= ((xi >> k) & 1) << (3 * k + 2);
        }
        c |= ((xi >> 4) & 1) << 12;
        c |= ((yi >> 4) & 1) << 13;
        code[j] = c;
        atomicAdd(&cnt[c >> 1], (c & 1) ? 0x10000u : 1u);
    }
    __syncthreads();

    unsigned int w[8];
    int tot = 0;
#pragma unroll
    for (int k = 0; k < 8; ++k) {
        w[k] = cnt[t * 8 + k];
        tot += (int)(w[k] & 0xffffu) + (int)(w[k] >> 16);
    }
    int inc = tot;
#pragma unroll
    for (int off = 1; off < 64; off <<= 1) {
        int v = __shfl_up(inc, off);
        if (lane >= off) inc += v;
    }
    if (lane == 63) s_wsum[wave] = inc;
    __syncthreads();
    int wbase = 0;
#pragma unroll
    for (int q = 0; q < 16; ++q) {
        int v = s_wsum[q];
        if (q < wave) wbase += v;
    }
    int excl = wbase + inc - tot;
#pragma unroll
    for (int k = 0; k < 8; ++k) {
        unsigned int c0 = (unsigned int)excl;
        unsigned int c1 = c0 + (w[k] & 0xffffu);
        cnt[t * 8 + k] = c0 | (c1 << 16);
        excl = (int)(c1 + (w[k] >> 16));
    }
    __syncthreads();

#pragma unroll
    for (int j = 0; j < 16; ++j) {
        int i = t + j * NT_MS;
        int c = code[j];
        unsigned int old = atomicAdd(&cnt[c >> 1], (c & 1) ? 0x10000u : 1u);
        int pos = (c & 1) ? (int)(old >> 16) : (int)(old & 0xffffu);
        sb[pos] = make_float4(xx[j], yy[j], zz[j], __int_as_float(i));
    }
}

// ============ Kernel 1: dense pruned FPS (one block per cloud) ==============
// 1024 threads x 16-pt Morton chunk. Register state sized to the PROVEN
// 64-VGPR grant at 1024 threads: z[16]+dd[16]=32 regs + bbox(6) + temps.
// (x,y) pairs live in LDS (u64, permuted addr j*1024+t -> 8B lane stride,
// conflict-free); winner resolution is ONE barrier: per-wave (key,z) partials
// in parity-double-buffered LDS, all threads scan 16 entries, winner (x,y)
// via broadcast LDS read. Tie-break = lowest Morton rank packed in key low
// bits (exact f32 d^2 argmax ties are measure-zero on this random input;
// rounds 1-11 absmax=0). seq writes deferred to a final pass (s_win ring)
// so no global latency sits on the per-step chain.
#define NT_FP 1024
#define CPT 16
#define NW_FP (NT_FP / 64)   // 16 waves

__global__ __launch_bounds__(NT_FP, 1)
void fps_pruned_kernel(const float* __restrict__ pts, const float4* __restrict__ sbuf,
                       int* __restrict__ seq) {
    const int b = blockIdx.x, t = threadIdx.x;
    const int lane = t & 63, wave = t >> 6;
    const float4* sb = sbuf + (size_t)b * N;

    __shared__ unsigned long long s_xy[N];            // 128 KB: lo=x, hi=y
    __shared__ unsigned long long s_pk[2][NW_FP];     // parity dbuf partial keys
    __shared__ float s_pz[2][NW_FP];                  // partial z
    __shared__ unsigned short s_win[S];               // winner Morton ranks

    float z[CPT], dd[CPT];
    float bx0 = BIG, by0 = BIG, bz0 = BIG, bx1 = -BIG, by1 = -BIG, bz1 = -BIG;
#pragma unroll
    for (int j = 0; j < CPT; ++j) {
        float4 v = sb[t * CPT + j];
        s_xy[j * NT_FP + t] =
            ((unsigned long long)__float_as_uint(v.y) << 32) |
            __float_as_uint(v.x);
        z[j] = v.z; dd[j] = BIG;
        bx0 = fminf(bx0, v.x); bx1 = fmaxf(bx1, v.x);
        by0 = fminf(by0, v.y); by1 = fmaxf(by1, v.y);
        bz0 = fminf(bz0, v.z); bz1 = fmaxf(bz1, v.z);
    }
    asm volatile("" : "+v"(bx0), "+v"(by0), "+v"(bz0), "+v"(bx1), "+v"(by1), "+v"(bz1));

    if (t == 0) seq[b * S + 0] = 0;        // first sample (random_start=False)
    const float* p = pts + (size_t)b * N * 3;
    float lx = p[0], ly = p[1], lz = p[2];
    // chunk candidate (key, z) and cached wave candidate; overwritten at step
    // 1 (all chunks hot) before first real use
    unsigned long long bkey =
        ((unsigned long long)__float_as_uint(BIG) << 32) |
        (unsigned int)(16383 - t * CPT);
    float bz = z[0];
    unsigned long long wkey = 0ull;
    float wz = 0.0f;
    __syncthreads();

    for (int step = 1; step < S; ++step) {
        // conservative bbox lower bound; margin covers f32 rounding (validated
        // absmax=0 across rounds 3-11)
        float tx = fmaxf(fmaxf(bx0 - lx, lx - bx1), 0.0f);
        float ty = fmaxf(fmaxf(by0 - ly, ly - by1), 0.0f);
        float tz = fmaxf(fmaxf(bz0 - lz, lz - bz1), 0.0f);
        float lb = tx * tx + ty * ty + tz * tz;
        float bmax = __uint_as_float((unsigned int)(bkey >> 32));
        bool upd = (lb * 0.999998f < bmax);
        if (__any(upd)) {
            if (upd) {
                unsigned long long k = 0ull;
                float kz = 0.0f;
#pragma unroll
                for (int j = 0; j < CPT; ++j) {
                    unsigned long long xy = s_xy[j * NT_FP + t];
                    float x = __uint_as_float((unsigned int)xy);
                    float y = __uint_as_float((unsigned int)(xy >> 32));
                    // Exact f32, no FMA contraction: ((dx*dx + dy*dy) + dz*dz)
                    float dx = __fsub_rn(x, lx);
                    float dy = __fsub_rn(y, ly);
                    float dz = __fsub_rn(z[j], lz);
                    float d  = __fadd_rn(__fadd_rn(__fmul_rn(dx, dx),
                               __fmul_rn(dy, dy)), __fmul_rn(dz, dz));
                    float nd = fminf(dd[j], d);     // exact, order-independent
                    dd[j] = nd;
                    unsigned long long pk =
                        ((unsigned long long)__float_as_uint(nd) << 32) |
                        (unsigned int)(16383 - (t * CPT + j));
                    if (pk > k) { k = pk; kz = z[j]; }
                }
                bkey = k; bz = kz;
            }
            // wave argmax (u64: value, then lowest Morton rank); carry z
            unsigned long long r = bkey;
#pragma unroll
            for (int off = 32; off >= 1; off >>= 1) {
                unsigned long long o = __shfl_xor(r, off);
                r = (o > r) ? o : r;
            }
            unsigned long long mask = __ballot(bkey == r);  // unique owner
            int wl = (int)__builtin_ctzll(mask);
            wkey = r;
            wz = __shfl(bz, wl);
        }
        if (lane == 0) {
            s_pk[step & 1][wave] = wkey;
            s_pz[step & 1][wave] = wz;
        }
        __syncthreads();

        // all threads scan the 16 wave partials (broadcast reads)
        unsigned long long g = 0ull;
        int gw = 0;
#pragma unroll
        for (int q = 0; q < NW_FP; ++q) {
            unsigned long long kq = s_pk[step & 1][q];
            if (kq > g) { g = kq; gw = q; }
        }
        int mrank = 16383 - (int)(g & 0x3fffu);
        unsigned long long xy = s_xy[(mrank & (CPT - 1)) * NT_FP + (mrank >> 4)];
        lx = __uint_as_float((unsigned int)xy);
        ly = __uint_as_float((unsigned int)(xy >> 32));
        lz = s_pz[step & 1][gw];
        if (t == 0) s_win[step] = (unsigned short)mrank;
    }
    __syncthreads();
    // resolve winner Morton ranks -> original indices (off the serial chain)
    for (int st = 1 + t; st < S; st += NT_FP) {
        int mrank = s_win[st];
        seq[b * S + st] = __float_as_int(sb[mrank].w);
    }
}

// ============ Fallback FPS (used only if ws too small) ======================
#define NT_FPS 512
#define PPT (N / NT_FPS)
#define NWAVE (NT_FPS / 64)
__global__ __launch_bounds__(NT_FPS)
void fps_kernel(const float* __restrict__ pts, int* __restrict__ seq) {
    const int b = blockIdx.x;
    const float* p = pts + (size_t)b * N * 3;
    const int t = threadIdx.x;
    const int lane = t & 63;
    const int wave = t >> 6;
    float px[PPT], py[PPT], pz[PPT], dd[PPT];
    const int base = t * PPT;
#pragma unroll
    for (int j = 0; j < PPT; ++j) {
        px[j] = p[(base + j) * 3 + 0];
        py[j] = p[(base + j) * 3 + 1];
        pz[j] = p[(base + j) * 3 + 2];
        dd[j] = BIG;
    }
#pragma unroll
    for (int j = 0; j < PPT; ++j)
        asm volatile("" : "+v"(px[j]), "+v"(py[j]), "+v"(pz[j]));
    __shared__ unsigned long long s_part[2][NWAVE];
    if (t == 0) seq[b * S + 0] = 0;
    float lx = p[0], ly = p[1], lz = p[2];
    for (int step = 1; step < S; ++step) {
        float bv = -1.0f;
        int bi = 0;
#pragma unroll
        for (int j = 0; j < PPT; ++j) {
            float dx = __fsub_rn(px[j], lx);
            float dy = __fsub_rn(py[j], ly);
            float dz = __fsub_rn(pz[j], lz);
            float d  = __fadd_rn(__fadd_rn(__fmul_rn(dx, dx), __fmul_rn(dy, dy)),
                                 __fmul_rn(dz, dz));
            float nd = fminf(dd[j], d);
            dd[j] = nd;
            if (nd > bv) { bv = nd; bi = base + j; }
        }
        unsigned long long key =
            ((unsigned long long)__float_as_uint(bv) << 32) | (unsigned int)(~bi);
#pragma unroll
        for (int off = 32; off >= 1; off >>= 1) {
            unsigned long long o = __shfl_down(key, off);
            if (o > key) key = o;
        }
        if (lane == 0) s_part[step & 1][wave] = key;
        __syncthreads();
        unsigned long long bk = s_part[step & 1][0];
#pragma unroll
        for (int q = 1; q < NWAVE; ++q) {
            unsigned long long o = s_part[step & 1][q];
            if (o > bk) bk = o;
        }
        int wi = (int)(~(unsigned int)bk);
        if (t == 0) seq[b * S + step] = wi;
        int wis = __builtin_amdgcn_readfirstlane(wi);
        lx = p[wis * 3 + 0];
        ly = p[wis * 3 + 1];
        lz = p[wis * 3 + 2];
    }
}

// ============ Kernel 2: sort FPS indices (bitmap rank), gather dst ==========
#define NT_SORT 512
__global__ __launch_bounds__(NT_SORT)
void sort_gather_kernel(const float* __restrict__ pts, const int* __restrict__ seq,
                        int* __restrict__ sorted, float* __restrict__ out) {
    const int b = blockIdx.x;
    const int t = threadIdx.x;
    __shared__ unsigned int bm[N / 32];
    __shared__ int pfx[N / 32];
    __shared__ int s_sorted[S];

    for (int i = t; i < N / 32; i += NT_SORT) bm[i] = 0u;
    __syncthreads();
    for (int i = t; i < S; i += NT_SORT) {
        int v = seq[b * S + i];
        atomicOr(&bm[v >> 5], 1u << (v & 31));
    }
    __syncthreads();

    int myc = __popc(bm[t]);
    pfx[t] = myc;
    __syncthreads();
    for (int off = 1; off < N / 32; off <<= 1) {
        int v = (t >= off) ? pfx[t - off] : 0;
        __syncthreads();
        pfx[t] += v;
        __syncthreads();
    }

    for (int i = t; i < S; i += NT_SORT) {
        int v = seq[b * S + i];
        int w = v >> 5;
        int rank = pfx[w] - __popc(bm[w]) + __popc(bm[w] & ((1u << (v & 31)) - 1u));
        s_sorted[rank] = v;
    }
    __syncthreads();

    for (int r = t; r < S; r += NT_SORT) {
        int v = s_sorted[r];
        int g = b * S + r;
        sorted[g] = v;
        out[OFF_COORD + 3 * (size_t)g + 0] = pts[((size_t)b * N + v) * 3 + 0];
        out[OFF_COORD + 3 * (size_t)g + 1] = pts[((size_t)b * N + v) * 3 + 1];
        out[OFF_COORD + 3 * (size_t)g + 2] = pts[((size_t)b * N + v) * 3 + 2];
        out[OFF_BATCH + g] = (float)b;
        out[OFF_NIDX + g]  = (float)(v + b * N);
    }
}

// ============ Kernel 3: radius ball query, one wave per dst point ===========
#define CAP 512
__global__ __launch_bounds__(256)
void ballq_kernel(const float* __restrict__ pts, const int* __restrict__ sorted,
                  float* __restrict__ out) {
    const int w    = threadIdx.x >> 6;
    const int lane = threadIdx.x & 63;
    const int g    = blockIdx.x * 4 + w;
    const int b    = g >> 12;
    const float R2 = (float)(0.08 * 0.08);

    __shared__ float cd2[4][CAP];
    __shared__ int   cidx[4][CAP];
    __shared__ int   coor[4][K];

    const float Dx = out[OFF_COORD + 3 * (size_t)g + 0];
    const float Dy = out[OFF_COORD + 3 * (size_t)g + 1];
    const float Dz = out[OFF_COORD + 3 * (size_t)g + 2];
    const int self = sorted[g];

    const float* p = pts + (size_t)b * N * 3;
    const unsigned long long ltmask = (lane == 63) ? 0x7fffffffffffffffull
                                                   : ((1ull << lane) - 1ull);
    int cnt = 0, oor = 0;
    for (int i0 = 0; i0 < N; i0 += 64) {
        int i = i0 + lane;
        float dx = __fsub_rn(Dx, p[i * 3 + 0]);
        float dy = __fsub_rn(Dy, p[i * 3 + 1]);
        float dz = __fsub_rn(Dz, p[i * 3 + 2]);
        float d2 = __fadd_rn(__fadd_rn(__fmul_rn(dx, dx), __fmul_rn(dy, dy)),
                             __fmul_rn(dz, dz));
        bool in = (d2 <= R2);
        unsigned long long m = __ballot(in);
        if (in) {
            int pos = cnt + __popcll(m & ltmask);
            if (pos < CAP) { cd2[w][pos] = d2; cidx[w][pos] = i; }
        }
        if (oor < K) {
            unsigned long long m2 = ~m;
            if (!in) {
                int p2 = oor + __popcll(m2 & ltmask);
                if (p2 < K) coor[w][p2] = i;
            }
            oor += __popcll(m2);
            if (oor > K) oor = K;
        }
        cnt += __popcll(m);
    }

    const int M  = cnt < CAP ? cnt : CAP;
    const int Mk = M < K ? M : K;
    const size_t eb = (size_t)g * K;
    int deg = 0;
    for (int c = lane; c < M; c += 64) {
        float myd = cd2[w][c];
        int   myi = cidx[w][c];
        int rank = 0;
        for (int j = 0; j < M; ++j) {
            float dj = cd2[w][j];
            int   ij = cidx[w][j];
            rank += (dj < myd || (dj == myd && ij < myi)) ? 1 : 0;
        }
        if (rank < K) {
            bool valid = (myi != self);
            out[OFF_ESRC + eb + rank] = (float)(myi + b * N);
            out[OFF_MASK + eb + rank] = valid ? 1.0f : 0.0f;
            deg += valid ? 1 : 0;
        }
    }
    for (int r = lane; r < K; r += 64) {
        out[OFF_EDST + eb + r] = (float)g;
        if (r >= Mk) {
            out[OFF_ESRC + eb + r] = (float)(coor[w][r - Mk] + b * N);
            out[OFF_MASK + eb + r] = 0.0f;
        }
    }
#pragma unroll
    for (int off = 32; off >= 1; off >>= 1) deg += __shfl_down(deg, off);
    if (lane == 0) out[OFF_DEG + g] = (float)deg;
}

extern "C" void kernel_launch(void* const* d_in, const int* in_sizes, int n_in,
                              void* d_out, int out_size, void* d_ws, size_t ws_size,
                              hipStream_t stream) {
    const float* pts = (const float*)d_in[0];
    float* out = (float*)d_out;

    const size_t sbuf_bytes = (size_t)B * N * sizeof(float4);   // 1 MB
    const size_t need = sbuf_bytes + 2 * (size_t)B * S * sizeof(int);

    if (ws_size >= need) {
        float4* sbuf = (float4*)d_ws;
        int* seq    = (int*)((char*)d_ws + sbuf_bytes);
        int* sorted = seq + (size_t)B * S;
        morton_sort_kernel<<<B, NT_MS, 0, stream>>>(pts, sbuf);
        fps_pruned_kernel<<<B, NT_FP, 0, stream>>>(pts, sbuf, seq);
        sort_gather_kernel<<<B, NT_SORT, 0, stream>>>(pts, seq, sorted, out);
        ballq_kernel<<<(B * S) / 4, 256, 0, stream>>>(pts, sorted, out);
    } else {
        int* seq    = (int*)d_ws;
        int* sorted = seq + (size_t)B * S;
        fps_kernel<<<B, NT_FPS, 0, stream>>>(pts, seq);
        sort_gather_kernel<<<B, NT_SORT, 0, stream>>>(pts, seq, sorted, out);
        ballq_kernel<<<(B * S) / 4, 256, 0, stream>>>(pts, sorted, out);
    }
}